// Round 5
// baseline (121.112 us; speedup 1.0000x reference)
//
#include <hip/hip_runtime.h>
#include <math.h>

#define KDIM 512
#define NDIM 4096
#define MEMD 64
#define WTAPS 16

#define GBM 64
#define GBN 64
#define GBK 64

typedef short bf16x8 __attribute__((ext_vector_type(8)));
typedef float f32x4 __attribute__((ext_vector_type(4)));

#define GLOAD_LDS16(g, l) __builtin_amdgcn_global_load_lds( \
    (const __attribute__((address_space(1))) unsigned int*)(g), \
    (__attribute__((address_space(3))) unsigned int*)(l), 16, 0, 0)

// ---- bf16 hi/lo split (RTNE) ----
__device__ __forceinline__ void bsplit(float a, ushort& hi, ushort& lo) {
    uint u = __float_as_uint(a);
    uint h = (u + 0x7FFFu + ((u >> 16) & 1u)) >> 16;
    hi = (ushort)h;
    float hf = __uint_as_float(h << 16);
    float r = a - hf;                       // exact (Sterbenz)
    uint u2 = __float_as_uint(r);
    lo = (ushort)((u2 + 0x7FFFu + ((u2 >> 16) & 1u)) >> 16);
}

__device__ __forceinline__ float block_reduce_256(float v, float* sbuf) {
    #pragma unroll
    for (int off = 32; off > 0; off >>= 1) v += __shfl_down(v, off, 64);
    int lane = threadIdx.x & 63, wid = threadIdx.x >> 6;
    if (lane == 0) sbuf[wid] = v;
    __syncthreads();
    float tot = sbuf[0] + sbuf[1] + sbuf[2] + sbuf[3];
    __syncthreads();
    return tot;
}

__device__ __forceinline__ double block_reduce_256d(double v, double* dbuf) {
    #pragma unroll
    for (int off = 32; off > 0; off >>= 1) v += __shfl_down(v, off, 64);
    int lane = threadIdx.x & 63, wid = threadIdx.x >> 6;
    if (lane == 0) dbuf[wid] = v;
    __syncthreads();
    double tot = dbuf[0] + dbuf[1] + dbuf[2] + dbuf[3];
    __syncthreads();
    return tot;
}

// ---- fused conversion: B transpose+split (blocks 0..2047), A split (blocks 2048..2175) ----
__global__ __launch_bounds__(256) void conv_kernel(
    const float* __restrict__ B, const float* __restrict__ A,
    ushort* __restrict__ Bthi, ushort* __restrict__ Btlo,
    ushort* __restrict__ Ahi, ushort* __restrict__ Alo,
    unsigned int* __restrict__ cnt) {
    __shared__ float s[32][33];
    int b = blockIdx.x, tid = threadIdx.x;
    if (b < 2048) {
        int n0 = (b & 127) * 32, k0 = (b >> 7) * 32;
        int r = tid >> 5, c = tid & 31;
        #pragma unroll
        for (int i = 0; i < 4; ++i)
            s[r + i * 8][c] = B[(size_t)(k0 + r + i * 8) * NDIM + n0 + c];
        __syncthreads();
        int rr = tid >> 4, cc = (tid & 15) * 2;
        #pragma unroll
        for (int i = 0; i < 2; ++i) {
            int n = rr + i * 16;
            float a0 = s[cc][n], a1 = s[cc + 1][n];
            ushort h0, l0, h1, l1;
            bsplit(a0, h0, l0); bsplit(a1, h1, l1);
            size_t o = (size_t)(n0 + n) * KDIM + k0 + cc;
            *(ushort2*)&Bthi[o] = make_ushort2(h0, h1);
            *(ushort2*)&Btlo[o] = make_ushort2(l0, l1);
        }
    } else {
        int ab = b - 2048;
        if (ab == 0 && tid == 0) *cnt = 0u;
        int g = ab * 256 + tid;
        const float4* src = (const float4*)A;
        #pragma unroll
        for (int i = 0; i < 2; ++i) {
            float4 v = src[g * 2 + i];
            ushort4 h, l;
            bsplit(v.x, h.x, l.x); bsplit(v.y, h.y, l.y);
            bsplit(v.z, h.z, l.z); bsplit(v.w, h.w, l.w);
            *(ushort4*)&Ahi[(size_t)g * 8 + i * 4] = h;
            *(ushort4*)&Alo[(size_t)g * 8 + i * 4] = l;
        }
    }
}

// ---- T = alpha @ obs via split-bf16 MFMA; global_load_lds staging ----
// LDS layout: linear chunks; chunk d = plane*512 + row*8 + swz_kc, swz_kc = kc ^ (row&7).
// Staging writes lane-linear dest (d = c), source pre-inverse-swizzled; ds_read applies swizzle.
__global__ __launch_bounds__(256) void mfma_gemm(
    const ushort* __restrict__ Ahi, const ushort* __restrict__ Alo,
    const ushort* __restrict__ Bthi, const ushort* __restrict__ Btlo,
    float* __restrict__ C) {
    __shared__ __align__(16) ushort Asm[2][GBM * GBK];
    __shared__ __align__(16) ushort Bsm[2][GBN * GBK];
    int tid = threadIdx.x;
    int m0 = blockIdx.y * GBM, n0 = blockIdx.x * GBN;
    int l = tid & 63, w = tid >> 6;
    int wm = w >> 1, wn = w & 1;
    int lr = l & 15, lk = l >> 4;

    f32x4 acc[2][2];
    #pragma unroll
    for (int i = 0; i < 2; ++i)
        #pragma unroll
        for (int j = 0; j < 2; ++j) acc[i][j] = (f32x4){0.f, 0.f, 0.f, 0.f};

    for (int c0 = 0; c0 < KDIM; c0 += GBK) {
        #pragma unroll
        for (int i = 0; i < 4; ++i) {
            int c = tid + i * 256;                   // linear chunk id, lane-consecutive
            int plane = c >> 9, q = c & 511;
            int row = q >> 3, kc = (q & 7) ^ (row & 7);
            const ushort* sa = (plane ? Alo : Ahi) + (size_t)(m0 + row) * KDIM + c0 + kc * 8;
            GLOAD_LDS16(sa, (char*)&Asm[0][0] + c * 16);
            const ushort* sb = (plane ? Btlo : Bthi) + (size_t)(n0 + row) * KDIM + c0 + kc * 8;
            GLOAD_LDS16(sb, (char*)&Bsm[0][0] + c * 16);
        }
        __syncthreads();
        bf16x8 ah[2][2], al[2][2], bh[2][2], bl[2][2];   // [frag][k-slice]
        #pragma unroll
        for (int mf = 0; mf < 2; ++mf)
            #pragma unroll
            for (int s = 0; s < 2; ++s) {
                int ra = wm * 32 + mf * 16 + lr;
                int offa = ra * 128 + (((s * 64) + lk * 16) ^ ((ra & 7) << 4));
                ah[mf][s] = *(const bf16x8*)((const char*)&Asm[0][0] + offa);
                al[mf][s] = *(const bf16x8*)((const char*)&Asm[1][0] + offa);
                int rb = wn * 32 + mf * 16 + lr;
                int offb = rb * 128 + (((s * 64) + lk * 16) ^ ((rb & 7) << 4));
                bh[mf][s] = *(const bf16x8*)((const char*)&Bsm[0][0] + offb);
                bl[mf][s] = *(const bf16x8*)((const char*)&Bsm[1][0] + offb);
            }
        #pragma unroll
        for (int s = 0; s < 2; ++s)
            #pragma unroll
            for (int mf = 0; mf < 2; ++mf)
                #pragma unroll
                for (int nf = 0; nf < 2; ++nf) {
                    acc[mf][nf] = __builtin_amdgcn_mfma_f32_16x16x32_bf16(ah[mf][s], bh[nf][s], acc[mf][nf], 0, 0, 0);
                    acc[mf][nf] = __builtin_amdgcn_mfma_f32_16x16x32_bf16(ah[mf][s], bl[nf][s], acc[mf][nf], 0, 0, 0);
                    acc[mf][nf] = __builtin_amdgcn_mfma_f32_16x16x32_bf16(al[mf][s], bh[nf][s], acc[mf][nf], 0, 0, 0);
                }
        __syncthreads();
    }
    #pragma unroll
    for (int mf = 0; mf < 2; ++mf)
        #pragma unroll
        for (int nf = 0; nf < 2; ++nf)
            #pragma unroll
            for (int j = 0; j < 4; ++j) {
                int rm = m0 + wm * 32 + mf * 16 + lk * 4 + j;
                int cn = n0 + wn * 32 + nf * 16 + lr;
                C[(size_t)rm * NDIM + cn] = acc[mf][nf][j];
            }
}

// ---- swizzled LDS chunk helpers (16B chunks; XOR spreads stride-64B windows) ----
__device__ __forceinline__ int chunk_off(int cch) {
    return ((cch & ~7) | ((cch ^ (cch >> 3)) & 7)) * 16;
}
__device__ __forceinline__ float4 lds_chunk(const float* buf, int cch) {
    return *(const float4*)((const char*)buf + chunk_off(cch));
}
__device__ __forceinline__ void lds_chunk_store(float* buf, int cch, float4 v) {
    *(float4*)((char*)buf + chunk_off(cch)) = v;
}

// ---- fused: mu + 16-tap decay filter + 64-tap depthwise conv + softplus + loglik
//      + last-block deterministic f64 reduction ----
__global__ __launch_bounds__(256) void final_kernel(
    const float* __restrict__ T, const float* __restrict__ obs,
    const float* __restrict__ extobs, const float* __restrict__ gamma,
    const float* __restrict__ beta_p,
    float* __restrict__ lams_out, double* __restrict__ partials,
    unsigned int* __restrict__ cnt, float* __restrict__ loglik_out) {
    __shared__ float Trow[NDIM];
    __shared__ float Erow[NDIM];
    __shared__ float Orow[NDIM];
    __shared__ float Grow[MEMD];
    __shared__ float sbuf[4];
    __shared__ double dbuf[4];
    __shared__ unsigned int flagS;

    int k = blockIdx.x, tid = threadIdx.x;
    float beta = *beta_p;

    const float4* t4 = (const float4*)(T + (size_t)k * NDIM);
    const float4* e4 = (const float4*)(extobs + (size_t)k * NDIM);
    const float4* o4 = (const float4*)(obs + (size_t)k * NDIM);

    float osum = 0.f;
    #pragma unroll
    for (int i = 0; i < 4; ++i) {
        int c = tid + i * 256;
        lds_chunk_store(Trow, c, t4[c]);
        lds_chunk_store(Erow, c, e4[c]);
        float4 o = o4[c];
        lds_chunk_store(Orow, c, o);
        osum += (o.x + o.y) + (o.z + o.w);
    }
    if (tid < MEMD) Grow[tid] = gamma[(size_t)k * MEMD + tid];

    float wtap[WTAPS];
    #pragma unroll
    for (int m = 0; m < WTAPS; ++m) wtap[m] = beta * expf(-beta * (float)(m + 1));

    float mu;
    {   // barrier inside also covers the LDS staging above
        float tot = block_reduce_256(osum, sbuf);
        mu = tot / (float)NDIM / 10.0f + 0.01f;
    }

    int t0 = tid * 16;

    // lam1: 16-tap decay FIR on T row; window T[t0-16 .. t0+15]
    float l1[16];
    #pragma unroll
    for (int j = 0; j < 16; ++j) l1[j] = 0.f;
    {
        float win[32];
        int cb = tid * 4 - 4;
        #pragma unroll
        for (int c = 0; c < 8; ++c) {
            int idx = cb + c;
            float4 x = (idx >= 0) ? lds_chunk(Trow, idx) : make_float4(0.f, 0.f, 0.f, 0.f);
            *(float4*)&win[c * 4] = x;
        }
        #pragma unroll
        for (int m = 1; m <= WTAPS; ++m) {
            float wm = wtap[m - 1];
            #pragma unroll
            for (int j = 0; j < 16; ++j) l1[j] = fmaf(wm, win[16 + j - m], l1[j]);
        }
    }

    // lam2: 64-tap depthwise causal correlation, chunked 4x16 taps (register-lean)
    float l2[16];
    #pragma unroll
    for (int j = 0; j < 16; ++j) l2[j] = 0.f;
    if (tid >= 4) {                                // t0 >= 64; tid<4 fully masked
        #pragma unroll
        for (int c4 = 0; c4 < 4; ++c4) {
            float win[32];
            int cb = tid * 4 - 16 + c4 * 4;
            #pragma unroll
            for (int c = 0; c < 8; ++c)
                *(float4*)&win[c * 4] = lds_chunk(Erow, cb + c);
            #pragma unroll
            for (int i = 0; i < 16; ++i) {
                float g = Grow[c4 * 16 + i];
                #pragma unroll
                for (int j = 0; j < 16; ++j) l2[j] = fmaf(g, win[i + j], l2[j]);
            }
        }
    }

    float* lrp = lams_out + (size_t)k * NDIM;
    double part = 0.0;
    #pragma unroll
    for (int i = 0; i < 4; ++i) {
        float4 o = lds_chunk(Orow, tid * 4 + i);
        float oo[4] = {o.x, o.y, o.z, o.w};
        f32x4 sv;
        #pragma unroll
        for (int q = 0; q < 4; ++q) {
            int j = i * 4 + q;
            float x = mu + l1[j] + l2[j];
            float sp = fmaxf(x, 0.f) + log1pf(expf(-fabsf(x)));   // jax softplus
            sv[q] = sp;
            part += (double)(oo[q] * logf(sp) - sp);
        }
        *(f32x4*)&lrp[t0 + i * 4] = sv;
    }
    double dtot = block_reduce_256d(part, dbuf);
    if (tid == 0) {
        partials[k] = dtot;
        __threadfence();
        unsigned int old = atomicAdd(cnt, 1u);
        flagS = (old == (unsigned int)(KDIM - 1)) ? 1u : 0u;
    }
    __syncthreads();
    if (flagS) {                                   // last block: deterministic f64 tree
        __threadfence();
        double v = 0.0;
        for (int j = tid; j < KDIM; j += 256) v += partials[j];
        double tot = block_reduce_256d(v, dbuf);
        if (tid == 0) loglik_out[0] = (float)tot;
    }
}

extern "C" void kernel_launch(void* const* d_in, const int* in_sizes, int n_in,
                              void* d_out, int out_size, void* d_ws, size_t ws_size,
                              hipStream_t stream) {
    const float* obs    = (const float*)d_in[0];
    const float* extobs = (const float*)d_in[1];
    const float* beta   = (const float*)d_in[2];
    const float* alpha  = (const float*)d_in[3];
    const float* gamma  = (const float*)d_in[4];
    float* out = (float*)d_out;

    char* ws = (char*)d_ws;
    float*  T        = (float*)(ws);                              // 8 MiB
    ushort* Bthi     = (ushort*)(ws + (8u << 20));                // 4 MiB
    ushort* Btlo     = (ushort*)(ws + (12u << 20));               // 4 MiB
    ushort* Ahi      = (ushort*)(ws + (16u << 20));               // 0.5 MiB
    ushort* Alo      = (ushort*)(ws + (16u << 20) + (512u << 10));// 0.5 MiB
    double* partials = (double*)(ws + (17u << 20));               // 4 KiB
    unsigned int* cnt = (unsigned int*)(ws + (17u << 20) + 4096); // 4 B

    conv_kernel<<<2048 + 128, 256, 0, stream>>>(obs, alpha, Bthi, Btlo, Ahi, Alo, cnt);
    mfma_gemm<<<dim3(NDIM / GBN, KDIM / GBM), 256, 0, stream>>>(Ahi, Alo, Bthi, Btlo, T);
    final_kernel<<<KDIM, 256, 0, stream>>>(T, obs, extobs, gamma, beta,
                                           out + 1, partials, cnt, out);
}